// Round 2
// baseline (252.595 us; speedup 1.0000x reference)
//
#include <hip/hip_runtime.h>
#include <hip/hip_bf16.h>

typedef __bf16 bf16x8 __attribute__((ext_vector_type(8)));
typedef float f32x4 __attribute__((ext_vector_type(4)));
typedef unsigned short ushort_t;
typedef unsigned short ushort8 __attribute__((ext_vector_type(8)));

// ---------- helpers ----------

__device__ inline void gload_lds16(const void* g, void* l) {
  __builtin_amdgcn_global_load_lds(
      (const __attribute__((address_space(1))) void*)g,
      (__attribute__((address_space(3))) void*)l, 16, 0, 0);
}

// fp32 -> bf16 round-to-nearest-even (bit manipulation, no API dependency)
__device__ inline ushort_t f2bf(float f) {
  unsigned int u = __float_as_uint(f);
  unsigned int lsb = (u >> 16) & 1u;
  u += 0x7fffu + lsb;
  return (ushort_t)(u >> 16);
}

// ---------- conversion kernels ----------

__global__ __launch_bounds__(256) void f32_to_bf16_vec(
    const float* __restrict__ in, ushort_t* __restrict__ out) {
  int i = (blockIdx.x * 256 + threadIdx.x) * 8;
  float4 a = *(const float4*)&in[i];
  float4 b = *(const float4*)&in[i + 4];
  ushort8 o;
  o[0] = f2bf(a.x); o[1] = f2bf(a.y); o[2] = f2bf(a.z); o[3] = f2bf(a.w);
  o[4] = f2bf(b.x); o[5] = f2bf(b.y); o[6] = f2bf(b.z); o[7] = f2bf(b.w);
  *(ushort8*)&out[i] = o;
}

// in [R][C] fp32 -> out [C][R] bf16 (LDS-tiled, +1 pad to kill bank conflicts)
__global__ __launch_bounds__(256) void transpose_f32_bf16(
    const float* __restrict__ in, ushort_t* __restrict__ out, int R, int C) {
  __shared__ float tile[32][33];
  const int tx = threadIdx.x & 31, ty = threadIdx.x >> 5;  // 32 x 8
  const int c0 = blockIdx.x * 32, r0 = blockIdx.y * 32;
#pragma unroll
  for (int i = 0; i < 32; i += 8)
    tile[ty + i][tx] = in[(size_t)(r0 + ty + i) * C + c0 + tx];
  __syncthreads();
#pragma unroll
  for (int i = 0; i < 32; i += 8)
    out[(size_t)(c0 + ty + i) * R + r0 + tx] = f2bf(tile[tx][ty + i]);
}

// ---------- GEMM: C = A @ B (+bias), A[M][K] bf16, BT[N][K] bf16 ----------
// 128x128 tile, BK=32, 4 waves (2x2), each wave 64x64 = 4x4 fragments.

template <bool OUT_BF16>
__global__ __launch_bounds__(256) void gemm_bt(
    const ushort_t* __restrict__ A, const ushort_t* __restrict__ BT,
    const float* __restrict__ bias, void* __restrict__ Cout,
    int M, int N, int K) {
  __shared__ ushort_t lA[128 * 32];
  __shared__ ushort_t lB[128 * 32];
  const int tid = threadIdx.x;
  const int lane = tid & 63;
  const int wave = tid >> 6;
  const int wr = wave >> 1, wc = wave & 1;
  const int l16 = lane & 15, lhi = lane >> 4;
  const int bx = blockIdx.x, by = blockIdx.y;

  // staging: thread t loads 16B: row = t>>2, col = (t&3)*8; two passes of 64 rows
  const ushort_t* gA = A + (size_t)(by * 128 + (tid >> 2)) * K + (tid & 3) * 8;
  const ushort_t* gB = BT + (size_t)(bx * 128 + (tid >> 2)) * K + (tid & 3) * 8;

  f32x4 acc[4][4] = {};

  for (int k0 = 0; k0 < K; k0 += 32) {
    gload_lds16(gA + k0, &lA[tid * 8]);
    gload_lds16(gA + k0 + (size_t)64 * K, &lA[tid * 8 + 2048]);
    gload_lds16(gB + k0, &lB[tid * 8]);
    gload_lds16(gB + k0 + (size_t)64 * K, &lB[tid * 8 + 2048]);
    __syncthreads();  // drains vmcnt before barrier

    bf16x8 af[4], bfr[4];
#pragma unroll
    for (int m = 0; m < 4; m++)
      af[m] = *(const bf16x8*)&lA[(wr * 64 + m * 16 + l16) * 32 + lhi * 8];
#pragma unroll
    for (int n = 0; n < 4; n++)
      bfr[n] = *(const bf16x8*)&lB[(wc * 64 + n * 16 + l16) * 32 + lhi * 8];
#pragma unroll
    for (int m = 0; m < 4; m++)
#pragma unroll
      for (int n = 0; n < 4; n++)
        acc[m][n] = __builtin_amdgcn_mfma_f32_16x16x32_bf16(af[m], bfr[n],
                                                            acc[m][n], 0, 0, 0);
    __syncthreads();
  }

  // epilogue: C/D layout col=lane&15, row=(lane>>4)*4+j
  const int r0 = by * 128 + wr * 64 + lhi * 4;
  const int c0 = bx * 128 + wc * 64 + l16;
#pragma unroll
  for (int m = 0; m < 4; m++)
#pragma unroll
    for (int n = 0; n < 4; n++) {
      const int col = c0 + n * 16;
      const float bv = bias[col];
#pragma unroll
      for (int j = 0; j < 4; j++) {
        const int row = r0 + m * 16 + j;
        const float v = acc[m][n][j] + bv;
        if (OUT_BF16)
          ((ushort_t*)Cout)[(size_t)row * N + col] = f2bf(v);
        else
          ((float*)Cout)[(size_t)row * N + col] = v;
      }
    }
}

// ---------- attention (softmax-free, causal) ----------
// kqv [B*T][3072] bf16: cols [0,1024)=K, [1024,2048)=Q, [2048,3072)=V.
// Block: one (b,h) x 128 Q rows. 4 waves, each 32 q-rows x 64 dh.
// K-tile = 64. S round-trips through LDS as bf16 for the PV MFMA.

__global__ __launch_bounds__(256) void attn_kernel(
    const ushort_t* __restrict__ kqv, ushort_t* __restrict__ ao) {
  __shared__ ushort_t lK[64 * 64];    // [tk][dh]
  __shared__ ushort_t lVT[64 * 64];   // [dh][tk]  (transposed V)
  __shared__ ushort_t lS[4][32 * 64]; // per-wave [32 q][64 tk]
  const int tid = threadIdx.x, lane = tid & 63, wave = tid >> 6;
  const int l16 = lane & 15, lhi = lane >> 4;
  const int qi = gridDim.x - 1 - blockIdx.x;  // heavy tiles first (LPT)
  const int bh = blockIdx.y;
  const int b = bh >> 4, h = bh & 15;
  const int q0 = qi * 128;
  const ushort_t* base = kqv + (size_t)b * 2048 * 3072;

  // Q fragments in registers: rows q0+wave*32+m*16+l16, k = ks*32+lhi*8
  bf16x8 qf[2][2];
#pragma unroll
  for (int m = 0; m < 2; m++)
#pragma unroll
    for (int ks = 0; ks < 2; ks++)
      qf[m][ks] = *(const bf16x8*)&base[(size_t)(q0 + wave * 32 + m * 16 + l16) * 3072 +
                                        1024 + h * 64 + ks * 32 + lhi * 8];

  f32x4 oacc[2][4] = {};
  const int nkt = q0 / 64 + 2;  // causal tiles
  const int sr = tid >> 3;          // 0..31
  const int sc = (tid & 7) * 8;     // 0..56

  for (int kt = 0; kt < nkt; ++kt) {
    __syncthreads();  // prior iteration's LDS reads done
    // stage K tile [64][64] (linear, global_load_lds)
#pragma unroll
    for (int p = 0; p < 2; p++)
      gload_lds16(&base[(size_t)(kt * 64 + sr + p * 32) * 3072 + h * 64 + sc],
                  &lK[tid * 8 + p * 2048]);
    // stage V transposed: lVT[d][tk]
#pragma unroll
    for (int p = 0; p < 2; p++) {
      const int rr = sr + p * 32;
      ushort8 v8 = *(const ushort8*)&base[(size_t)(kt * 64 + rr) * 3072 +
                                          2048 + h * 64 + sc];
#pragma unroll
      for (int j = 0; j < 8; j++) lVT[(sc + j) * 64 + rr] = v8[j];
    }
    __syncthreads();  // staging visible (incl. vmcnt drain)

    // S = Q K^T   (B-fragment of K^T == K row-major: free)
    f32x4 sacc[2][4] = {};
#pragma unroll
    for (int n = 0; n < 4; n++) {
      bf16x8 kf0 = *(const bf16x8*)&lK[(n * 16 + l16) * 64 + lhi * 8];
      bf16x8 kf1 = *(const bf16x8*)&lK[(n * 16 + l16) * 64 + 32 + lhi * 8];
#pragma unroll
      for (int m = 0; m < 2; m++) {
        sacc[m][n] = __builtin_amdgcn_mfma_f32_16x16x32_bf16(qf[m][0], kf0, sacc[m][n], 0, 0, 0);
        sacc[m][n] = __builtin_amdgcn_mfma_f32_16x16x32_bf16(qf[m][1], kf1, sacc[m][n], 0, 0, 0);
      }
    }

    // causal mask (diagonal tiles only) + bf16 convert + write to LDS
    const bool need_mask = (kt * 64 + 63) > (q0 + wave * 32);
#pragma unroll
    for (int m = 0; m < 2; m++)
#pragma unroll
      for (int n = 0; n < 4; n++)
#pragma unroll
        for (int j = 0; j < 4; j++) {
          float s = sacc[m][n][j];
          if (need_mask) {
            const int row = q0 + wave * 32 + m * 16 + lhi * 4 + j;
            const int col = kt * 64 + n * 16 + l16;
            if (col > row) s = 0.f;
          }
          lS[wave][(m * 16 + lhi * 4 + j) * 64 + n * 16 + l16] = f2bf(s);
        }
    __syncthreads();  // S + V visible

    // O += S @ V  (A = S from LDS, B^T = VT)
#pragma unroll
    for (int ks = 0; ks < 2; ++ks) {
      bf16x8 sf[2];
#pragma unroll
      for (int m = 0; m < 2; m++)
        sf[m] = *(const bf16x8*)&lS[wave][(m * 16 + l16) * 64 + ks * 32 + lhi * 8];
#pragma unroll
      for (int n = 0; n < 4; n++) {
        bf16x8 vf = *(const bf16x8*)&lVT[(n * 16 + l16) * 64 + ks * 32 + lhi * 8];
#pragma unroll
        for (int m = 0; m < 2; m++)
          oacc[m][n] = __builtin_amdgcn_mfma_f32_16x16x32_bf16(sf[m], vf, oacc[m][n], 0, 0, 0);
      }
    }
  }

  // write O -> ao [B*T][1024] bf16
#pragma unroll
  for (int m = 0; m < 2; m++)
#pragma unroll
    for (int n = 0; n < 4; n++)
#pragma unroll
      for (int j = 0; j < 4; j++) {
        const int row = q0 + wave * 32 + m * 16 + lhi * 4 + j;
        const int col = h * 64 + n * 16 + l16;
        ao[(size_t)(b * 2048 + row) * 1024 + col] = f2bf(oacc[m][n][j]);
      }
}

// ---------- launch ----------

extern "C" void kernel_launch(void* const* d_in, const int* in_sizes, int n_in,
                              void* d_out, int out_size, void* d_ws, size_t ws_size,
                              hipStream_t stream) {
  const float* x  = (const float*)d_in[0];
  const float* W1 = (const float*)d_in[1];
  const float* b1 = (const float*)d_in[2];
  const float* W2 = (const float*)d_in[3];
  const float* b2 = (const float*)d_in[4];
  float* out = (float*)d_out;

  char* ws = (char*)d_ws;
  ushort_t* xb  = (ushort_t*)(ws);                 //  8 MB: x bf16 [4096][1024]
  ushort_t* w1t = (ushort_t*)(ws + 8388608);       //  6 MB: W1^T bf16 [3072][1024]
  ushort_t* w2t = (ushort_t*)(ws + 14680064);      //  2 MB: W2^T bf16 [1024][1024]
  ushort_t* kqv = (ushort_t*)(ws + 16777216);      // 24 MB: kqv bf16 [4096][3072]
  ushort_t* ao  = (ushort_t*)(ws + 41943040);      //  8 MB: attn out bf16 [4096][1024]

  f32_to_bf16_vec<<<2048, 256, 0, stream>>>(x, xb);                       // 4096*1024
  transpose_f32_bf16<<<dim3(96, 32), 256, 0, stream>>>(W1, w1t, 1024, 3072);
  transpose_f32_bf16<<<dim3(32, 32), 256, 0, stream>>>(W2, w2t, 1024, 1024);
  gemm_bt<true ><<<dim3(24, 32), 256, 0, stream>>>(xb, w1t, b1, kqv, 4096, 3072, 1024);
  attn_kernel<<<dim3(16, 32), 256, 0, stream>>>(kqv, ao);
  gemm_bt<false><<<dim3(8, 32), 256, 0, stream>>>(ao, w2t, b2, out, 4096, 1024, 1024);
}

// Round 4
// 210.487 us; speedup vs baseline: 1.2001x; 1.2001x over previous
//
#include <hip/hip_runtime.h>
#include <hip/hip_bf16.h>

typedef __bf16 bf16x8 __attribute__((ext_vector_type(8)));
typedef float f32x4 __attribute__((ext_vector_type(4)));
typedef unsigned short ushort_t;
typedef unsigned short ushort8 __attribute__((ext_vector_type(8)));

// ---------- helpers ----------

__device__ inline void gload_lds16(const void* g, void* l) {
  __builtin_amdgcn_global_load_lds(
      (const __attribute__((address_space(1))) void*)g,
      (__attribute__((address_space(3))) void*)l, 16, 0, 0);
}

// fp32 -> bf16 round-to-nearest-even (bit manipulation)
__device__ inline ushort_t f2bf(float f) {
  unsigned int u = __float_as_uint(f);
  unsigned int lsb = (u >> 16) & 1u;
  u += 0x7fffu + lsb;
  return (ushort_t)(u >> 16);
}

// ---------- conversion kernels ----------

__global__ __launch_bounds__(256) void f32_to_bf16_vec(
    const float* __restrict__ in, ushort_t* __restrict__ out) {
  int i = (blockIdx.x * 256 + threadIdx.x) * 8;
  float4 a = *(const float4*)&in[i];
  float4 b = *(const float4*)&in[i + 4];
  ushort8 o;
  o[0] = f2bf(a.x); o[1] = f2bf(a.y); o[2] = f2bf(a.z); o[3] = f2bf(a.w);
  o[4] = f2bf(b.x); o[5] = f2bf(b.y); o[6] = f2bf(b.z); o[7] = f2bf(b.w);
  *(ushort8*)&out[i] = o;
}

// in [R][C] fp32 -> out [C][R] bf16 (LDS-tiled)
__global__ __launch_bounds__(256) void transpose_f32_bf16(
    const float* __restrict__ in, ushort_t* __restrict__ out, int R, int C) {
  __shared__ float tile[32][33];
  const int tx = threadIdx.x & 31, ty = threadIdx.x >> 5;  // 32 x 8
  const int c0 = blockIdx.x * 32, r0 = blockIdx.y * 32;
#pragma unroll
  for (int i = 0; i < 32; i += 8)
    tile[ty + i][tx] = in[(size_t)(r0 + ty + i) * C + c0 + tx];
  __syncthreads();
#pragma unroll
  for (int i = 0; i < 32; i += 8)
    out[(size_t)(c0 + ty + i) * R + r0 + tx] = f2bf(tile[tx][ty + i]);
}

// V-part of kqv [4096][3072] -> vt[bh][64 dh][2048 t]  (bf16 transpose)
__global__ __launch_bounds__(256) void transpose_v(
    const ushort_t* __restrict__ kqv, ushort_t* __restrict__ vt) {
  __shared__ ushort_t tile[64 * 64];  // 16B-slot XOR swizzle
  const int tt = blockIdx.x;  // t tile (0..31)
  const int bh = blockIdx.y;  // 0..31
  const int b = bh >> 4, h = bh & 15;
  const int tid = threadIdx.x;
  // load 64 t-rows x 64 dh (coalesced), swizzled 16B-slot store
#pragma unroll
  for (int p = 0; p < 2; p++) {
    const int tr = (tid >> 3) + p * 32;
    const int c8 = tid & 7;
    ushort8 v = *(const ushort8*)&kqv[(size_t)(b * 2048 + tt * 64 + tr) * 3072 +
                                      2048 + h * 64 + c8 * 8];
    *(ushort8*)&tile[tr * 64 + ((c8 ^ (tr & 7)) * 8)] = v;
  }
  __syncthreads();
  // write: lane d = tid&63 (full spread -> conflict-free column reads)
  const int d = tid & 63;
#pragma unroll
  for (int p = 0; p < 2; p++) {
    const int t8 = (tid >> 6) + p * 4;  // 8-t chunk 0..7
    ushort8 o;
#pragma unroll
    for (int j = 0; j < 8; j++) {
      const int t = t8 * 8 + j;
      o[j] = tile[t * 64 + (((d >> 3) ^ (t & 7)) * 8) + (d & 7)];
    }
    *(ushort8*)&vt[(size_t)(bh * 64 + d) * 2048 + tt * 64 + t8 * 8] = o;
  }
}

// ---------- GEMM: C = A @ B (+bias), A[M][K] bf16, BT[N][K] bf16 ----------
// (unchanged — known-good m97 structure)

template <bool OUT_BF16>
__global__ __launch_bounds__(256) void gemm_bt(
    const ushort_t* __restrict__ A, const ushort_t* __restrict__ BT,
    const float* __restrict__ bias, void* __restrict__ Cout,
    int M, int N, int K) {
  __shared__ ushort_t lA[128 * 32];
  __shared__ ushort_t lB[128 * 32];
  const int tid = threadIdx.x;
  const int lane = tid & 63;
  const int wave = tid >> 6;
  const int wr = wave >> 1, wc = wave & 1;
  const int l16 = lane & 15, lhi = lane >> 4;
  const int bx = blockIdx.x, by = blockIdx.y;

  const ushort_t* gA = A + (size_t)(by * 128 + (tid >> 2)) * K + (tid & 3) * 8;
  const ushort_t* gB = BT + (size_t)(bx * 128 + (tid >> 2)) * K + (tid & 3) * 8;

  f32x4 acc[4][4] = {};

  for (int k0 = 0; k0 < K; k0 += 32) {
    gload_lds16(gA + k0, &lA[tid * 8]);
    gload_lds16(gA + k0 + (size_t)64 * K, &lA[tid * 8 + 2048]);
    gload_lds16(gB + k0, &lB[tid * 8]);
    gload_lds16(gB + k0 + (size_t)64 * K, &lB[tid * 8 + 2048]);
    __syncthreads();

    bf16x8 af[4], bfr[4];
#pragma unroll
    for (int m = 0; m < 4; m++)
      af[m] = *(const bf16x8*)&lA[(wr * 64 + m * 16 + l16) * 32 + lhi * 8];
#pragma unroll
    for (int n = 0; n < 4; n++)
      bfr[n] = *(const bf16x8*)&lB[(wc * 64 + n * 16 + l16) * 32 + lhi * 8];
#pragma unroll
    for (int m = 0; m < 4; m++)
#pragma unroll
      for (int n = 0; n < 4; n++)
        acc[m][n] = __builtin_amdgcn_mfma_f32_16x16x32_bf16(af[m], bfr[n],
                                                            acc[m][n], 0, 0, 0);
    __syncthreads();
  }

  const int r0 = by * 128 + wr * 64 + lhi * 4;
  const int c0 = bx * 128 + wc * 64 + l16;
#pragma unroll
  for (int m = 0; m < 4; m++)
#pragma unroll
    for (int n = 0; n < 4; n++) {
      const int col = c0 + n * 16;
      const float bv = bias[col];
#pragma unroll
      for (int j = 0; j < 4; j++) {
        const int row = r0 + m * 16 + j;
        const float v = acc[m][n][j] + bv;
        if (OUT_BF16)
          ((ushort_t*)Cout)[(size_t)row * N + col] = f2bf(v);
        else
          ((float*)Cout)[(size_t)row * N + col] = v;
      }
    }
}

// ---------- attention (softmax-free, causal) ----------
// 512 threads = 8 waves; block = (b,h) x 128 Q rows; wave = 16 q-rows x dh=64.
// K-tile = 64. K and V^T staged via global_load_lds with pre-swizzled source
// (XOR (row&7)<<4 on byte col); all ds_reads use the matching swizzle.
// lS is per-wave (same-wave DS ordering -> no barrier); ONE barrier per tile.

__global__ __launch_bounds__(512) void attn_kernel(
    const ushort_t* __restrict__ kqv, const ushort_t* __restrict__ vt,
    ushort_t* __restrict__ ao) {
  __shared__ ushort_t lK[2][64 * 64];
  __shared__ ushort_t lVT[2][64 * 64];
  __shared__ ushort_t lS[8][16 * 64];
  const int tid = threadIdx.x, lane = tid & 63, wave = tid >> 6;
  const int l16 = lane & 15, lhi = lane >> 4;
  const int qi = gridDim.x - 1 - blockIdx.x;  // heavy tiles first (LPT)
  const int bh = blockIdx.y;
  const int b = bh >> 4, h = bh & 15;
  const int q0 = qi * 128;
  const ushort_t* base = kqv + (size_t)b * 2048 * 3072;
  const ushort_t* vbase = vt + (size_t)bh * 64 * 2048;

  // staging coords: row = tid>>3 (0..63), 16B chunk = tid&7; swizzled source
  const int srow = tid >> 3;
  const int scb_src = ((tid & 7) * 16) ^ ((srow & 7) << 4);  // byte offset
  const size_t kg = (size_t)srow * 3072 + h * 64 + (scb_src >> 1);
  const size_t vg = (size_t)srow * 2048 + (scb_src >> 1);

  // Q fragments in registers (wave's 16 rows)
  const int wq0 = q0 + wave * 16;
  bf16x8 qf[2];
#pragma unroll
  for (int ks = 0; ks < 2; ks++)
    qf[ks] = *(const bf16x8*)&base[(size_t)(wq0 + l16) * 3072 + 1024 + h * 64 +
                                   ks * 32 + lhi * 8];

  f32x4 oacc[4] = {};
  const int nkt = q0 / 64 + 2;  // causal K tiles

  int cur = 0;
  // prologue stage tile 0
  gload_lds16(&base[(size_t)0 * 64 * 3072 + kg], &lK[0][tid * 8]);
  gload_lds16(&vbase[vg], &lVT[0][tid * 8]);
  __syncthreads();

  for (int kt = 0; kt < nkt; ++kt) {
    if (kt + 1 < nkt) {  // prefetch next tile into other buffer
      gload_lds16(&base[(size_t)(kt + 1) * 64 * 3072 + kg], &lK[cur ^ 1][tid * 8]);
      gload_lds16(&vbase[(size_t)(kt + 1) * 64 + vg], &lVT[cur ^ 1][tid * 8]);
    }

    // S = Q K^T (swizzled lK reads)
    f32x4 sacc[4] = {};
#pragma unroll
    for (int n = 0; n < 4; n++) {
      const int kr = n * 16 + l16;
      const int sw = (kr & 7) << 3;
      bf16x8 kf0 = *(const bf16x8*)&lK[cur][kr * 64 + ((lhi * 8) ^ sw)];
      bf16x8 kf1 = *(const bf16x8*)&lK[cur][kr * 64 + ((32 + lhi * 8) ^ sw)];
      sacc[n] = __builtin_amdgcn_mfma_f32_16x16x32_bf16(qf[0], kf0, sacc[n], 0, 0, 0);
      sacc[n] = __builtin_amdgcn_mfma_f32_16x16x32_bf16(qf[1], kf1, sacc[n], 0, 0, 0);
    }

    // causal mask + bf16 + per-wave S store (swizzled)
    const bool need_mask = (kt * 64 + 63) > wq0;
#pragma unroll
    for (int n = 0; n < 4; n++)
#pragma unroll
      for (int j = 0; j < 4; j++) {
        float s = sacc[n][j];
        const int r = lhi * 4 + j;
        if (need_mask && (kt * 64 + n * 16 + l16) > (wq0 + r)) s = 0.f;
        __bf16 hv = (__bf16)s;
        lS[wave][r * 64 + ((n * 16 + l16) ^ ((r & 7) << 3))] =
            __builtin_bit_cast(ushort_t, hv);
      }

    // O += S @ V (own-wave lS: same-wave DS order, no barrier needed)
#pragma unroll
    for (int ks = 0; ks < 2; ks++) {
      bf16x8 sf = *(const bf16x8*)&lS[wave][l16 * 64 +
                                            ((ks * 32 + lhi * 8) ^ ((l16 & 7) << 3))];
#pragma unroll
      for (int n = 0; n < 4; n++) {
        const int dr = n * 16 + l16;
        bf16x8 vf = *(const bf16x8*)&lVT[cur][dr * 64 +
                                              ((ks * 32 + lhi * 8) ^ ((dr & 7) << 3))];
        oacc[n] = __builtin_amdgcn_mfma_f32_16x16x32_bf16(sf, vf, oacc[n], 0, 0, 0);
      }
    }

    __syncthreads();  // drains vmcnt (prefetch) + lgkm; next tile ready
    cur ^= 1;
  }

  // write O -> ao [B*T][1024] bf16
#pragma unroll
  for (int n = 0; n < 4; n++)
#pragma unroll
    for (int j = 0; j < 4; j++) {
      const int row = wq0 + lhi * 4 + j;
      const int col = h * 64 + n * 16 + l16;
      ao[(size_t)(b * 2048 + row) * 1024 + col] = f2bf(oacc[n][j]);
    }
}

// ---------- launch ----------

extern "C" void kernel_launch(void* const* d_in, const int* in_sizes, int n_in,
                              void* d_out, int out_size, void* d_ws, size_t ws_size,
                              hipStream_t stream) {
  const float* x  = (const float*)d_in[0];
  const float* W1 = (const float*)d_in[1];
  const float* b1 = (const float*)d_in[2];
  const float* W2 = (const float*)d_in[3];
  const float* b2 = (const float*)d_in[4];
  float* out = (float*)d_out;

  char* ws = (char*)d_ws;
  ushort_t* xb  = (ushort_t*)(ws);                 //  8 MB: x bf16 [4096][1024]
  ushort_t* w1t = (ushort_t*)(ws + 8388608);       //  6 MB: W1^T bf16 [3072][1024]
  ushort_t* w2t = (ushort_t*)(ws + 14680064);      //  2 MB: W2^T bf16 [1024][1024]
  ushort_t* kqv = (ushort_t*)(ws + 16777216);      // 24 MB: kqv bf16 [4096][3072]
  ushort_t* ao  = (ushort_t*)(ws + 41943040);      //  8 MB: attn out bf16 [4096][1024]
  ushort_t* vtb = (ushort_t*)(ws);                 //  8 MB: V^T (aliases xb; xb dead after gemm1)

  f32_to_bf16_vec<<<2048, 256, 0, stream>>>(x, xb);
  transpose_f32_bf16<<<dim3(96, 32), 256, 0, stream>>>(W1, w1t, 1024, 3072);
  transpose_f32_bf16<<<dim3(32, 32), 256, 0, stream>>>(W2, w2t, 1024, 1024);
  gemm_bt<true ><<<dim3(24, 32), 256, 0, stream>>>(xb, w1t, b1, kqv, 4096, 3072, 1024);
  transpose_v<<<dim3(32, 32), 256, 0, stream>>>(kqv, vtb);
  attn_kernel<<<dim3(16, 32), 512, 0, stream>>>(kqv, vtb, ao);
  gemm_bt<false><<<dim3(8, 32), 256, 0, stream>>>(ao, w2t, b2, out, 4096, 1024, 1024);
}

// Round 5
// 209.309 us; speedup vs baseline: 1.2068x; 1.0056x over previous
//
#include <hip/hip_runtime.h>
#include <hip/hip_bf16.h>

typedef __bf16 bf16x8 __attribute__((ext_vector_type(8)));
typedef float f32x4 __attribute__((ext_vector_type(4)));
typedef unsigned short ushort_t;
typedef unsigned short ushort8 __attribute__((ext_vector_type(8)));

// ---------- helpers ----------

__device__ inline void gload_lds16(const void* g, void* l) {
  __builtin_amdgcn_global_load_lds(
      (const __attribute__((address_space(1))) void*)g,
      (__attribute__((address_space(3))) void*)l, 16, 0, 0);
}

// fp32 -> bf16 round-to-nearest-even (bit manipulation)
__device__ inline ushort_t f2bf(float f) {
  unsigned int u = __float_as_uint(f);
  unsigned int lsb = (u >> 16) & 1u;
  u += 0x7fffu + lsb;
  return (ushort_t)(u >> 16);
}

// ---------- conversion kernels ----------

__global__ __launch_bounds__(256) void f32_to_bf16_vec(
    const float* __restrict__ in, ushort_t* __restrict__ out) {
  int i = (blockIdx.x * 256 + threadIdx.x) * 8;
  float4 a = *(const float4*)&in[i];
  float4 b = *(const float4*)&in[i + 4];
  ushort8 o;
  o[0] = f2bf(a.x); o[1] = f2bf(a.y); o[2] = f2bf(a.z); o[3] = f2bf(a.w);
  o[4] = f2bf(b.x); o[5] = f2bf(b.y); o[6] = f2bf(b.z); o[7] = f2bf(b.w);
  *(ushort8*)&out[i] = o;
}

// in [R][C] fp32 -> out [C][R] bf16 (LDS-tiled)
__global__ __launch_bounds__(256) void transpose_f32_bf16(
    const float* __restrict__ in, ushort_t* __restrict__ out, int R, int C) {
  __shared__ float tile[32][33];
  const int tx = threadIdx.x & 31, ty = threadIdx.x >> 5;  // 32 x 8
  const int c0 = blockIdx.x * 32, r0 = blockIdx.y * 32;
#pragma unroll
  for (int i = 0; i < 32; i += 8)
    tile[ty + i][tx] = in[(size_t)(r0 + ty + i) * C + c0 + tx];
  __syncthreads();
#pragma unroll
  for (int i = 0; i < 32; i += 8)
    out[(size_t)(c0 + ty + i) * R + r0 + tx] = f2bf(tile[tx][ty + i]);
}

// V-part of kqv [4096][3072] -> vt[bh][64 dh][2048 t]  (bf16 transpose)
__global__ __launch_bounds__(256) void transpose_v(
    const ushort_t* __restrict__ kqv, ushort_t* __restrict__ vt) {
  __shared__ ushort_t tile[64 * 64];  // 16B-slot XOR swizzle
  const int tt = blockIdx.x;  // t tile (0..31)
  const int bh = blockIdx.y;  // 0..31
  const int b = bh >> 4, h = bh & 15;
  const int tid = threadIdx.x;
#pragma unroll
  for (int p = 0; p < 2; p++) {
    const int tr = (tid >> 3) + p * 32;
    const int c8 = tid & 7;
    ushort8 v = *(const ushort8*)&kqv[(size_t)(b * 2048 + tt * 64 + tr) * 3072 +
                                      2048 + h * 64 + c8 * 8];
    *(ushort8*)&tile[tr * 64 + ((c8 ^ (tr & 7)) * 8)] = v;
  }
  __syncthreads();
  const int d = tid & 63;
#pragma unroll
  for (int p = 0; p < 2; p++) {
    const int t8 = (tid >> 6) + p * 4;  // 8-t chunk 0..7
    ushort8 o;
#pragma unroll
    for (int j = 0; j < 8; j++) {
      const int t = t8 * 8 + j;
      o[j] = tile[t * 64 + (((d >> 3) ^ (t & 7)) * 8) + (d & 7)];
    }
    *(ushort8*)&vt[(size_t)(bh * 64 + d) * 2048 + tt * 64 + t8 * 8] = o;
  }
}

// ---------- GEMM: C = A @ B (+bias), A[M][K] bf16, BT[N][K] bf16 ----------
// (unchanged — known-good m97 structure; control)

template <bool OUT_BF16>
__global__ __launch_bounds__(256) void gemm_bt(
    const ushort_t* __restrict__ A, const ushort_t* __restrict__ BT,
    const float* __restrict__ bias, void* __restrict__ Cout,
    int M, int N, int K) {
  __shared__ ushort_t lA[128 * 32];
  __shared__ ushort_t lB[128 * 32];
  const int tid = threadIdx.x;
  const int lane = tid & 63;
  const int wave = tid >> 6;
  const int wr = wave >> 1, wc = wave & 1;
  const int l16 = lane & 15, lhi = lane >> 4;
  const int bx = blockIdx.x, by = blockIdx.y;

  const ushort_t* gA = A + (size_t)(by * 128 + (tid >> 2)) * K + (tid & 3) * 8;
  const ushort_t* gB = BT + (size_t)(bx * 128 + (tid >> 2)) * K + (tid & 3) * 8;

  f32x4 acc[4][4] = {};

  for (int k0 = 0; k0 < K; k0 += 32) {
    gload_lds16(gA + k0, &lA[tid * 8]);
    gload_lds16(gA + k0 + (size_t)64 * K, &lA[tid * 8 + 2048]);
    gload_lds16(gB + k0, &lB[tid * 8]);
    gload_lds16(gB + k0 + (size_t)64 * K, &lB[tid * 8 + 2048]);
    __syncthreads();

    bf16x8 af[4], bfr[4];
#pragma unroll
    for (int m = 0; m < 4; m++)
      af[m] = *(const bf16x8*)&lA[(wr * 64 + m * 16 + l16) * 32 + lhi * 8];
#pragma unroll
    for (int n = 0; n < 4; n++)
      bfr[n] = *(const bf16x8*)&lB[(wc * 64 + n * 16 + l16) * 32 + lhi * 8];
#pragma unroll
    for (int m = 0; m < 4; m++)
#pragma unroll
      for (int n = 0; n < 4; n++)
        acc[m][n] = __builtin_amdgcn_mfma_f32_16x16x32_bf16(af[m], bfr[n],
                                                            acc[m][n], 0, 0, 0);
    __syncthreads();
  }

  const int r0 = by * 128 + wr * 64 + lhi * 4;
  const int c0 = bx * 128 + wc * 64 + l16;
#pragma unroll
  for (int m = 0; m < 4; m++)
#pragma unroll
    for (int n = 0; n < 4; n++) {
      const int col = c0 + n * 16;
      const float bv = bias[col];
#pragma unroll
      for (int j = 0; j < 4; j++) {
        const int row = r0 + m * 16 + j;
        const float v = acc[m][n][j] + bv;
        if (OUT_BF16)
          ((ushort_t*)Cout)[(size_t)row * N + col] = f2bf(v);
        else
          ((float*)Cout)[(size_t)row * N + col] = v;
      }
    }
}

// ---------- attention (softmax-free, causal) ----------
// 512 threads = 8 waves; block = (b,h) x 128 Q rows; wave = 16 q-rows x dh=64.
// K-tile = 64; 3 LDS buffers, depth-2 prefetch with counted s_waitcnt vmcnt(2)
// + raw s_barrier (T3/T4): loads for tile t+2 issued at tile t, never drained
// to 0 in steady state. XCD-bijective block swizzle (T1): 4 bh per XCD.
// XOR-swizzled K/V^T/S (verified: 0 bank conflicts in round 4).

__global__ __launch_bounds__(512) void attn_kernel(
    const ushort_t* __restrict__ kqv, const ushort_t* __restrict__ vt,
    ushort_t* __restrict__ ao) {
  __shared__ ushort_t lK[3][64 * 64];
  __shared__ ushort_t lVT[3][64 * 64];
  __shared__ ushort_t lS[8][16 * 64];
  const int tid = threadIdx.x, lane = tid & 63, wave = tid >> 6;
  const int l16 = lane & 15, lhi = lane >> 4;
  // XCD swizzle: work W = (L%8)*64 + L/8; qi heavy-first; bh = W/16.
  const int L = blockIdx.x;
  const int W = (L & 7) * 64 + (L >> 3);
  const int qi = 15 - (W & 15);
  const int bh = W >> 4;
  const int b = bh >> 4, h = bh & 15;
  const int q0 = qi * 128;
  const ushort_t* base = kqv + (size_t)b * 2048 * 3072;
  const ushort_t* vbase = vt + (size_t)bh * 64 * 2048;

  // staging coords: row = tid>>3 (0..63), 16B chunk = tid&7; pre-swizzled src
  const int srow = tid >> 3;
  const int scb_src = ((tid & 7) * 16) ^ ((srow & 7) << 4);  // byte offset
  const size_t kg = (size_t)srow * 3072 + h * 64 + (scb_src >> 1);
  const size_t vg = (size_t)srow * 2048 + (scb_src >> 1);

  // Q fragments in registers (wave's 16 rows)
  const int wq0 = q0 + wave * 16;
  bf16x8 qf[2];
#pragma unroll
  for (int ks = 0; ks < 2; ks++)
    qf[ks] = *(const bf16x8*)&base[(size_t)(wq0 + l16) * 3072 + 1024 + h * 64 +
                                   ks * 32 + lhi * 8];

  f32x4 oacc[4] = {};
  const int nkt = q0 / 64 + 2;  // causal K tiles (>= 2 always)

  // prologue: stage tiles 0 and 1 (both exist since nkt >= 2)
  gload_lds16(&base[kg], &lK[0][tid * 8]);
  gload_lds16(&vbase[vg], &lVT[0][tid * 8]);
  gload_lds16(&base[(size_t)64 * 3072 + kg], &lK[1][tid * 8]);
  gload_lds16(&vbase[64 + vg], &lVT[1][tid * 8]);

  int cur = 0;
  for (int kt = 0; kt < nkt; ++kt) {
    // own tile-kt loads done (2 newest = tile kt+1 may stay in flight)
    if (kt + 1 < nkt) asm volatile("s_waitcnt vmcnt(2)" ::: "memory");
    else              asm volatile("s_waitcnt vmcnt(0)" ::: "memory");
    __builtin_amdgcn_s_barrier();
    asm volatile("" ::: "memory");

    // prefetch tile kt+2 into the buffer last read at iteration kt-1
    if (kt + 2 < nkt) {
      const int pf = (cur + 2 >= 3) ? cur - 1 : cur + 2;
      gload_lds16(&base[(size_t)(kt + 2) * 64 * 3072 + kg], &lK[pf][tid * 8]);
      gload_lds16(&vbase[(size_t)(kt + 2) * 64 + vg], &lVT[pf][tid * 8]);
    }

    // wave-uniform skip: tile entirely above the diagonal for this wave
    if (kt * 64 <= wq0 + 15) {
      // S = Q K^T (swizzled lK reads)
      f32x4 sacc[4] = {};
#pragma unroll
      for (int n = 0; n < 4; n++) {
        const int kr = n * 16 + l16;
        const int sw = (kr & 7) << 3;
        bf16x8 kf0 = *(const bf16x8*)&lK[cur][kr * 64 + ((lhi * 8) ^ sw)];
        bf16x8 kf1 = *(const bf16x8*)&lK[cur][kr * 64 + ((32 + lhi * 8) ^ sw)];
        sacc[n] = __builtin_amdgcn_mfma_f32_16x16x32_bf16(qf[0], kf0, sacc[n], 0, 0, 0);
        sacc[n] = __builtin_amdgcn_mfma_f32_16x16x32_bf16(qf[1], kf1, sacc[n], 0, 0, 0);
      }

      // causal mask + bf16 + per-wave S store (swizzled)
      const bool need_mask = (kt * 64 + 63) > wq0;
#pragma unroll
      for (int n = 0; n < 4; n++)
#pragma unroll
        for (int j = 0; j < 4; j++) {
          float s = sacc[n][j];
          const int r = lhi * 4 + j;
          if (need_mask && (kt * 64 + n * 16 + l16) > (wq0 + r)) s = 0.f;
          __bf16 hv = (__bf16)s;
          lS[wave][r * 64 + ((n * 16 + l16) ^ ((r & 7) << 3))] =
              __builtin_bit_cast(ushort_t, hv);
        }

      // O += S @ V (own-wave lS: same-wave DS order, no barrier needed)
#pragma unroll
      for (int ks = 0; ks < 2; ks++) {
        bf16x8 sf = *(const bf16x8*)&lS[wave][l16 * 64 +
                                              ((ks * 32 + lhi * 8) ^ ((l16 & 7) << 3))];
#pragma unroll
        for (int n = 0; n < 4; n++) {
          const int dr = n * 16 + l16;
          bf16x8 vf = *(const bf16x8*)&lVT[cur][dr * 64 +
                                                ((ks * 32 + lhi * 8) ^ ((dr & 7) << 3))];
          oacc[n] = __builtin_amdgcn_mfma_f32_16x16x32_bf16(sf, vf, oacc[n], 0, 0, 0);
        }
      }
    }

    cur = (cur + 1 >= 3) ? 0 : cur + 1;
  }

  // write O -> ao [B*T][1024] bf16
#pragma unroll
  for (int n = 0; n < 4; n++)
#pragma unroll
    for (int j = 0; j < 4; j++) {
      const int row = wq0 + lhi * 4 + j;
      const int col = h * 64 + n * 16 + l16;
      ao[(size_t)(b * 2048 + row) * 1024 + col] = f2bf(oacc[n][j]);
    }
}

// ---------- launch ----------

extern "C" void kernel_launch(void* const* d_in, const int* in_sizes, int n_in,
                              void* d_out, int out_size, void* d_ws, size_t ws_size,
                              hipStream_t stream) {
  const float* x  = (const float*)d_in[0];
  const float* W1 = (const float*)d_in[1];
  const float* b1 = (const float*)d_in[2];
  const float* W2 = (const float*)d_in[3];
  const float* b2 = (const float*)d_in[4];
  float* out = (float*)d_out;

  char* ws = (char*)d_ws;
  ushort_t* xb  = (ushort_t*)(ws);                 //  8 MB: x bf16 [4096][1024]
  ushort_t* w1t = (ushort_t*)(ws + 8388608);       //  6 MB: W1^T bf16 [3072][1024]
  ushort_t* w2t = (ushort_t*)(ws + 14680064);      //  2 MB: W2^T bf16 [1024][1024]
  ushort_t* kqv = (ushort_t*)(ws + 16777216);      // 24 MB: kqv bf16 [4096][3072]
  ushort_t* ao  = (ushort_t*)(ws + 41943040);      //  8 MB: attn out bf16 [4096][1024]
  ushort_t* vtb = (ushort_t*)(ws);                 //  8 MB: V^T (aliases xb; xb dead after gemm1)

  f32_to_bf16_vec<<<2048, 256, 0, stream>>>(x, xb);
  transpose_f32_bf16<<<dim3(96, 32), 256, 0, stream>>>(W1, w1t, 1024, 3072);
  transpose_f32_bf16<<<dim3(32, 32), 256, 0, stream>>>(W2, w2t, 1024, 1024);
  gemm_bt<true ><<<dim3(24, 32), 256, 0, stream>>>(xb, w1t, b1, kqv, 4096, 3072, 1024);
  transpose_v<<<dim3(32, 32), 256, 0, stream>>>(kqv, vtb);
  attn_kernel<<<dim3(512), 512, 0, stream>>>(kqv, vtb, ao);
  gemm_bt<false><<<dim3(8, 32), 256, 0, stream>>>(ao, w2t, b2, out, 4096, 1024, 1024);
}